// Round 3
// baseline (735.861 us; speedup 1.0000x reference)
//
#include <hip/hip_runtime.h>
#include <cstdint>

// out[b,s,o] = sum_k in[b,s,k] * lut[w[o,k]] + bias[o]
// GEMM: M=8192, N=4096, K=4096, fp32 out, f16 MFMA path.
//
// R6: 256x256 tile, BK=64, 8 waves (2Mx4N), 32x32x16 MFMA, pipelined phases.
//  - 4 phases/tile = 4 K-steps (s=0..3), 8 MFMA each (4m x 2n), BALANCED
//    6 ds_read/phase, issued ONE PHASE AHEAD into alternating reg sets
//    (A/B): lgkm(6) waits reads that already had ~500cy MFMA time to drain.
//  - mfma_f32_32x32x16_f16: faster pipe (2178+ vs 1955 TF ubench), half the
//    instruction count. acc[4][2] f32x16. C/D: col=lane&31,
//    row=(reg&3)+8*(reg>>2)+4*(lane>>5)  [m74/m101-verified].
//  - boundary folded into ph3: vmcnt(0)+barrier (Q-ready), read next-tile s0
//    from other buffer, issue stage(kt+2). vmcnt never blocks (loads are a
//    full tile old). kt-loop unrolled x2 for compile-time buffer indices.
//  - XOR chunk swizzle (slot c <-> global chunk c^(row&7)) kept: conflict-free
//    for the 32x32 frag pattern too (8-row groups permute all 8 slots).
// R5: 302us gemm, MfmaUtil 40% — reads serialized with MFMA (same-phase
// read+lgkm(0)+use). Predicted here: gemm ~165-200us, MfmaUtil ~60%.

static constexpr int Md = 8192;
static constexpr int Nd = 4096;
static constexpr int Kd = 4096;
static constexpr int NKT = Kd / 64;

typedef _Float16 half8 __attribute__((ext_vector_type(8)));
typedef float f32x16 __attribute__((ext_vector_type(16)));

__device__ __forceinline__ void async_copy16(const _Float16* g, _Float16* l) {
  __builtin_amdgcn_global_load_lds((const __attribute__((address_space(1))) void*)g,
                                   (__attribute__((address_space(3))) void*)l, 16, 0, 0);
}

__device__ __forceinline__ half8 lds_read_b128(uint32_t addr) {
  half8 r;
  asm volatile("ds_read_b128 %0, %1" : "=v"(r) : "v"(addr));
  return r;
}

#define LGKM(n) asm volatile("s_waitcnt lgkmcnt(" #n ")" ::: "memory")
#define VMCNT(n) asm volatile("s_waitcnt vmcnt(" #n ")" ::: "memory")
#define BAR() __builtin_amdgcn_s_barrier()
#define SB0() __builtin_amdgcn_sched_barrier(0)

// ---- convert input fp32 -> fp16, 8 elems/thread ----
__global__ __launch_bounds__(256) void cvt_a(const float* __restrict__ in,
                                             _Float16* __restrict__ out) {
  const size_t i = (size_t)blockIdx.x * 256 + threadIdx.x;
  const float4 x = ((const float4*)in)[2 * i];
  const float4 y = ((const float4*)in)[2 * i + 1];
  half8 h;
  h[0] = (_Float16)x.x; h[1] = (_Float16)x.y; h[2] = (_Float16)x.z; h[3] = (_Float16)x.w;
  h[4] = (_Float16)y.x; h[5] = (_Float16)y.y; h[6] = (_Float16)y.z; h[7] = (_Float16)y.w;
  *(half8*)(out + 8 * i) = h;
}

// ---- dequant weight idx -> fp16 via LDS-cached 256-entry LUT ----
__global__ __launch_bounds__(256) void dequant_b(const int* __restrict__ w,
                                                 const float* __restrict__ lut,
                                                 _Float16* __restrict__ out) {
  __shared__ float slut[256];
  slut[threadIdx.x] = lut[threadIdx.x];
  __syncthreads();
  const size_t i = (size_t)blockIdx.x * 256 + threadIdx.x;
  const int4 a = ((const int4*)w)[2 * i];
  const int4 b = ((const int4*)w)[2 * i + 1];
  half8 h;
  h[0] = (_Float16)slut[a.x]; h[1] = (_Float16)slut[a.y];
  h[2] = (_Float16)slut[a.z]; h[3] = (_Float16)slut[a.w];
  h[4] = (_Float16)slut[b.x]; h[5] = (_Float16)slut[b.y];
  h[6] = (_Float16)slut[b.z]; h[7] = (_Float16)slut[b.w];
  *(half8*)(out + 8 * i) = h;
}

// ---- C[M][N] = A[M][K] * Bt[N][K]^T + bias ----
__global__ __launch_bounds__(512, 2) void gemm_f16(const _Float16* __restrict__ A,
                                                   const _Float16* __restrict__ Bt,
                                                   const float* __restrict__ bias,
                                                   float* __restrict__ C) {
  __shared__ __align__(16) _Float16 As[2][256 * 64];
  __shared__ __align__(16) _Float16 Bs[2][256 * 64];

  const int tid = threadIdx.x;
  const int lane = tid & 63;
  const int wave = tid >> 6;
  const int wm = wave >> 2;  // 0..1
  const int wn = wave & 3;   // 0..3

  // XCD swizzle: 512 blocks -> 8 chunks of 64 consecutive on one XCD.
  const int bid0 = blockIdx.x + blockIdx.y * gridDim.x;  // grid (32,16)
  const int bid = (bid0 & 7) * 64 + (bid0 >> 3);
  const int bm = bid & 31;
  const int bn = bid >> 5;

  // ---- staging: 512 thr x 16B = 64 rows/issuance, 4 per half op.
  // LDS dest linear; swizzle on GLOBAL source chunk: slot (tid&7) gets
  // global chunk (tid&7)^(row&7).
  const int trow = tid >> 3;
  const int tcol = tid & 7;
  const int gch = tcol ^ (trow & 7);
  const _Float16* ag = A + (size_t)(bm * 256 + trow) * Kd + gch * 8;
  const _Float16* bg = Bt + (size_t)(bn * 256 + trow) * Kd + gch * 8;
  const int lds_off = trow * 64 + tcol * 8;

  auto stage = [&](int buf, int kt) {
#pragma unroll
    for (int ht = 0; ht < 4; ++ht) {
      async_copy16(ag + (size_t)kt * 64 + (size_t)ht * (64 * Kd),
                   &As[buf][lds_off + ht * 4096]);
      async_copy16(bg + (size_t)kt * 64 + (size_t)ht * (64 * Kd),
                   &Bs[buf][lds_off + ht * 4096]);
    }
  };

  // ---- fragment addressing, 32x32x16: lane l reads row (l&31), k-chunk
  // (2s + (l>>5)); chunk c of row r sits at LDS slot c^(r&7). Row = 128 B.
  const int l31 = lane & 31;
  const int hi = lane >> 5;
  const int e = lane & 7;
  const uint32_t as0 = (uint32_t)(uintptr_t)&As[0][0];
  const uint32_t bs0 = (uint32_t)(uintptr_t)&Bs[0][0];
  uint32_t ab[2][4], bb[2][4];
#pragma unroll
  for (int s = 0; s < 4; ++s) {
    const uint32_t off = (uint32_t)((((2 * s) + hi) ^ e) * 16);
    ab[0][s] = as0 + (uint32_t)((wm * 128 + l31) * 128) + off;
    ab[1][s] = ab[0][s] + 32768u;
    bb[0][s] = bs0 + (uint32_t)((wn * 64 + l31) * 128) + off;
    bb[1][s] = bb[0][s] + 32768u;
  }

  half8 aA[4], bA[2], aB[4], bB[2];
  f32x16 acc[4][2] = {};

#define READS(SET, AB, BB)                  \
  a##SET[0] = lds_read_b128((AB));          \
  a##SET[1] = lds_read_b128((AB) + 4096);   \
  a##SET[2] = lds_read_b128((AB) + 8192);   \
  a##SET[3] = lds_read_b128((AB) + 12288);  \
  b##SET[0] = lds_read_b128((BB));          \
  b##SET[1] = lds_read_b128((BB) + 4096);

#define MFMAS(SET)                                                                            \
  acc[0][0] = __builtin_amdgcn_mfma_f32_32x32x16_f16(a##SET[0], b##SET[0], acc[0][0], 0, 0, 0); \
  acc[0][1] = __builtin_amdgcn_mfma_f32_32x32x16_f16(a##SET[0], b##SET[1], acc[0][1], 0, 0, 0); \
  acc[1][0] = __builtin_amdgcn_mfma_f32_32x32x16_f16(a##SET[1], b##SET[0], acc[1][0], 0, 0, 0); \
  acc[1][1] = __builtin_amdgcn_mfma_f32_32x32x16_f16(a##SET[1], b##SET[1], acc[1][1], 0, 0, 0); \
  acc[2][0] = __builtin_amdgcn_mfma_f32_32x32x16_f16(a##SET[2], b##SET[0], acc[2][0], 0, 0, 0); \
  acc[2][1] = __builtin_amdgcn_mfma_f32_32x32x16_f16(a##SET[2], b##SET[1], acc[2][1], 0, 0, 0); \
  acc[3][0] = __builtin_amdgcn_mfma_f32_32x32x16_f16(a##SET[3], b##SET[0], acc[3][0], 0, 0, 0); \
  acc[3][1] = __builtin_amdgcn_mfma_f32_32x32x16_f16(a##SET[3], b##SET[1], acc[3][1], 0, 0, 0);

#define PHASE(RSET, AB, BB, CSET)       \
  READS(RSET, AB, BB);                  \
  BAR();                                \
  LGKM(6);                              \
  SB0();                                \
  __builtin_amdgcn_s_setprio(1);        \
  MFMAS(CSET);                          \
  __builtin_amdgcn_s_setprio(0);        \
  BAR();

  // prologue: stage tiles 0,1; wait tile 0 only; pre-read s0 of tile 0.
  stage(0, 0);
  stage(1, 1);
  VMCNT(8);
  BAR();
  READS(A, ab[0][0], bb[0][0]);

  for (int kt = 0; kt < NKT; kt += 2) {
    // ======== tile kt (buffer 0) ========
    PHASE(B, ab[0][1], bb[0][1], A);  // ph0: read s1, compute s0
    PHASE(A, ab[0][2], bb[0][2], B);  // ph1: read s2, compute s1
    PHASE(B, ab[0][3], bb[0][3], A);  // ph2: read s3, compute s2
    // ph3: boundary to tile kt+1 (buffer 1)
    VMCNT(0);  // tile kt+1's stage (issued a full tile ago) complete
    BAR();
    READS(A, ab[1][0], bb[1][0]);  // s0 of tile kt+1
    if (kt + 2 < NKT) stage(0, kt + 2);
    BAR();
    LGKM(6);
    SB0();
    __builtin_amdgcn_s_setprio(1);
    MFMAS(B);  // compute s3 of tile kt
    __builtin_amdgcn_s_setprio(0);
    BAR();

    // ======== tile kt+1 (buffer 1) ========
    PHASE(B, ab[1][1], bb[1][1], A);
    PHASE(A, ab[1][2], bb[1][2], B);
    PHASE(B, ab[1][3], bb[1][3], A);
    if (kt + 2 < NKT) {
      VMCNT(0);
      BAR();
      READS(A, ab[0][0], bb[0][0]);  // s0 of tile kt+2
      if (kt + 3 < NKT) stage(1, kt + 3);
      BAR();
      LGKM(6);
      SB0();
      __builtin_amdgcn_s_setprio(1);
      MFMAS(B);
      __builtin_amdgcn_s_setprio(0);
      BAR();
    } else {
      LGKM(0);
      SB0();
      __builtin_amdgcn_s_setprio(1);
      MFMAS(B);
      __builtin_amdgcn_s_setprio(0);
    }
  }

  // ---- epilogue: 32x32 C/D: col=lane&31, row=(reg&3)+8*(reg>>2)+4*(lane>>5)
  const int ccol0 = bn * 256 + wn * 64 + l31;
  const int crow0 = bm * 256 + wm * 128 + hi * 4;
  const float bv0 = bias[ccol0];
  const float bv1 = bias[ccol0 + 32];
#pragma unroll
  for (int m = 0; m < 4; ++m) {
#pragma unroll
    for (int r = 0; r < 16; ++r) {
      const int row = crow0 + m * 32 + (r & 3) + 8 * (r >> 2);
      float* cp = C + (size_t)row * Nd + ccol0;
      cp[0] = acc[m][0][r] + bv0;
      cp[32] = acc[m][1][r] + bv1;
    }
  }
}

extern "C" void kernel_launch(void* const* d_in, const int* in_sizes, int n_in,
                              void* d_out, int out_size, void* d_ws, size_t ws_size,
                              hipStream_t stream) {
  const float* inp = (const float*)d_in[0];
  const float* lut = (const float*)d_in[1];
  const int* wgt = (const int*)d_in[2];
  const float* bias = (const float*)d_in[3];
  float* out = (float*)d_out;

  _Float16* Ah = (_Float16*)d_ws;
  _Float16* Bh = (_Float16*)d_ws + (size_t)Md * Kd;

  cvt_a<<<(Md * (size_t)Kd) / (8 * 256), 256, 0, stream>>>(inp, Ah);
  dequant_b<<<((size_t)Nd * Kd) / (8 * 256), 256, 0, stream>>>(wgt, lut, Bh);

  dim3 grid(Md / 256, Nd / 256);  // (32, 16) = 512 blocks
  gemm_f16<<<grid, 512, 0, stream>>>(Ah, Bh, bias, out);
}

// Round 4
// 497.062 us; speedup vs baseline: 1.4804x; 1.4804x over previous
//
#include <hip/hip_runtime.h>
#include <cstdint>

// out[b,s,o] = sum_k in[b,s,k] * lut[w[o,k]] + bias[o]
// GEMM: M=8192, N=4096, K=4096, fp32 out, f16 MFMA path.
//
// R7: back to the R5-verified substrate (16x16x32 MFMA, quadrant phases,
// XOR chunk swizzle, asm ds_read_b128) + the two fixes R5's counters asked
// for:
//  - ONE-PHASE-AHEAD reads with counted lgkm: ph0(aL*b0) ph1(aL*b1)
//    ph2(aH*b1) ph3(aH*b0); b1 read during ph0, aH during ph1, NEXT tile's
//    aL+b0 during ph3. Each LGKM(n) waits reads issued ~500cy earlier.
//    b0 double-buffered by tile parity (only +16 VGPR).
//  - ONE barrier per tile (R5 had 5): vmcnt(0)+s_barrier at the boundary is
//    sufficient — each wave's LDS reads of the outgoing buffer are
//    lgkm-drained before it reaches the barrier, and the buffer being read
//    next was vmcnt-confirmed before the barrier.
//  - launch_bounds(512,1): LDS (128KB) caps at 1 block/CU anyway; full reg
//    headroom so nothing spills (R6's 5x WRITE_SIZE was scratch).
// R6 post-mortem: 32x32 + alternating-set pipeline = 2.5e7 LDS conflicts +
// 546MB/dispatch scratch spill -> 509us. Reverted both.
// R5: 302us gemm, MfmaUtil 40%. Predicted here: ~170-210us, MfmaUtil 55-70%.

static constexpr int Md = 8192;
static constexpr int Nd = 4096;
static constexpr int Kd = 4096;
static constexpr int NKT = Kd / 64;

typedef _Float16 half8 __attribute__((ext_vector_type(8)));
typedef float f32x4 __attribute__((ext_vector_type(4)));

__device__ __forceinline__ void async_copy16(const _Float16* g, _Float16* l) {
  __builtin_amdgcn_global_load_lds((const __attribute__((address_space(1))) void*)g,
                                   (__attribute__((address_space(3))) void*)l, 16, 0, 0);
}

#define LGKM(n) asm volatile("s_waitcnt lgkmcnt(" #n ")" ::: "memory")
#define VMCNT(n) asm volatile("s_waitcnt vmcnt(" #n ")" ::: "memory")
#define BAR() __builtin_amdgcn_s_barrier()
#define SB0() __builtin_amdgcn_sched_barrier(0)

// ds_read_b128 with literal offset; asm keeps hipcc from inserting vmcnt(0)
// RAW drains against global_load_lds (R5-verified win).
#define R16(dst, base, OFF) \
  asm volatile("ds_read_b128 %0, %1 offset:" #OFF : "=v"(dst) : "v"(base))

// ---- convert input fp32 -> fp16, 8 elems/thread ----
__global__ __launch_bounds__(256) void cvt_a(const float* __restrict__ in,
                                             _Float16* __restrict__ out) {
  const size_t i = (size_t)blockIdx.x * 256 + threadIdx.x;
  const float4 x = ((const float4*)in)[2 * i];
  const float4 y = ((const float4*)in)[2 * i + 1];
  half8 h;
  h[0] = (_Float16)x.x; h[1] = (_Float16)x.y; h[2] = (_Float16)x.z; h[3] = (_Float16)x.w;
  h[4] = (_Float16)y.x; h[5] = (_Float16)y.y; h[6] = (_Float16)y.z; h[7] = (_Float16)y.w;
  *(half8*)(out + 8 * i) = h;
}

// ---- dequant weight idx -> fp16 via LDS-cached 256-entry LUT ----
__global__ __launch_bounds__(256) void dequant_b(const int* __restrict__ w,
                                                 const float* __restrict__ lut,
                                                 _Float16* __restrict__ out) {
  __shared__ float slut[256];
  slut[threadIdx.x] = lut[threadIdx.x];
  __syncthreads();
  const size_t i = (size_t)blockIdx.x * 256 + threadIdx.x;
  const int4 a = ((const int4*)w)[2 * i];
  const int4 b = ((const int4*)w)[2 * i + 1];
  half8 h;
  h[0] = (_Float16)slut[a.x]; h[1] = (_Float16)slut[a.y];
  h[2] = (_Float16)slut[a.z]; h[3] = (_Float16)slut[a.w];
  h[4] = (_Float16)slut[b.x]; h[5] = (_Float16)slut[b.y];
  h[6] = (_Float16)slut[b.z]; h[7] = (_Float16)slut[b.w];
  *(half8*)(out + 8 * i) = h;
}

// ---- C[M][N] = A[M][K] * Bt[N][K]^T + bias ----
// 256x256 tile, BK=64, 8 waves (2Mx4N), per-wave 128x64 out, acc[8][4] f32x4.
__global__ __launch_bounds__(512, 1) void gemm_f16(const _Float16* __restrict__ A,
                                                   const _Float16* __restrict__ Bt,
                                                   const float* __restrict__ bias,
                                                   float* __restrict__ C) {
  __shared__ __align__(16) _Float16 As[2][256 * 64];
  __shared__ __align__(16) _Float16 Bs[2][256 * 64];

  const int tid = threadIdx.x;
  const int lane = tid & 63;
  const int wave = tid >> 6;
  const int wm = wave >> 2;  // 0..1
  const int wn = wave & 3;   // 0..3

  // XCD swizzle: 512 blocks -> 8 chunks of 64 consecutive per XCD.
  const int bid0 = blockIdx.x + blockIdx.y * gridDim.x;  // grid (32,16)
  const int bid = (bid0 & 7) * 64 + (bid0 >> 3);
  const int bm = bid & 31;
  const int bn = bid >> 5;

  // ---- staging: 512 thr x 16B = 64 rows/issuance, 4 per half op.
  // LDS dest linear; swizzle on GLOBAL source chunk: slot (tid&7) gets
  // global chunk (tid&7)^(row&7).
  const int trow = tid >> 3;
  const int tcol = tid & 7;
  const int gch = tcol ^ (trow & 7);
  const _Float16* ag = A + (size_t)(bm * 256 + trow) * Kd + gch * 8;
  const _Float16* bg = Bt + (size_t)(bn * 256 + trow) * Kd + gch * 8;
  const int lds_off = trow * 64 + tcol * 8;

  auto stage = [&](int buf, int kt) {
#pragma unroll
    for (int ht = 0; ht < 4; ++ht) {
      async_copy16(ag + (size_t)kt * 64 + (size_t)ht * (64 * Kd),
                   &As[buf][lds_off + ht * 4096]);
      async_copy16(bg + (size_t)kt * 64 + (size_t)ht * (64 * Kd),
                   &Bs[buf][lds_off + ht * 4096]);
    }
  };

  // ---- fragment addressing: chunk c of row r sits at slot c^(r&7); row=128B.
  // 16x16x32: fr=lane&15 row, fq=lane>>4 selects k-chunk (fq / 4|fq).
  const int fr = lane & 15;
  const int fq = lane >> 4;
  const int e = fr & 7;
  const uint32_t aS0 = (uint32_t)(uintptr_t)&As[0][0] +
                       (uint32_t)((wm * 128 + fr) * 128) + (uint32_t)((fq ^ e) * 16);
  const uint32_t aS1 = (uint32_t)(uintptr_t)&As[0][0] +
                       (uint32_t)((wm * 128 + fr) * 128) + (uint32_t)((((4 | fq) ^ e)) * 16);
  const uint32_t bS0 = (uint32_t)(uintptr_t)&Bs[0][0] +
                       (uint32_t)((wn * 64 + fr) * 128) + (uint32_t)((fq ^ e) * 16);
  const uint32_t bS1 = (uint32_t)(uintptr_t)&Bs[0][0] +
                       (uint32_t)((wn * 64 + fr) * 128) + (uint32_t)((((4 | fq) ^ e)) * 16);
  // buf1 = +32768 bytes, folded into the ds_read offset: immediates.

  half8 aL[4][2], aH[4][2], b0A[2][2], b0B[2][2], b1[2][2];
  f32x4 acc[8][4] = {};

  // 12-read entry set (aL + b0) for each buffer/parity:
#define R_ENTRY_B0()                                             \
  R16(aL[0][0], aS0, 0);     R16(aL[0][1], aS1, 0);              \
  R16(aL[1][0], aS0, 2048);  R16(aL[1][1], aS1, 2048);           \
  R16(aL[2][0], aS0, 4096);  R16(aL[2][1], aS1, 4096);           \
  R16(aL[3][0], aS0, 6144);  R16(aL[3][1], aS1, 6144);           \
  R16(b0A[0][0], bS0, 0);    R16(b0A[0][1], bS1, 0);             \
  R16(b0A[1][0], bS0, 2048); R16(b0A[1][1], bS1, 2048)

#define R_ENTRY_B1()                                             \
  R16(aL[0][0], aS0, 32768); R16(aL[0][1], aS1, 32768);          \
  R16(aL[1][0], aS0, 34816); R16(aL[1][1], aS1, 34816);          \
  R16(aL[2][0], aS0, 36864); R16(aL[2][1], aS1, 36864);          \
  R16(aL[3][0], aS0, 38912); R16(aL[3][1], aS1, 38912);          \
  R16(b0B[0][0], bS0, 32768); R16(b0B[0][1], bS1, 32768);        \
  R16(b0B[1][0], bS0, 34816); R16(b0B[1][1], bS1, 34816)

#define R_B1_0()                                                 \
  R16(b1[0][0], bS0, 4096);  R16(b1[0][1], bS1, 4096);           \
  R16(b1[1][0], bS0, 6144);  R16(b1[1][1], bS1, 6144)

#define R_B1_1()                                                 \
  R16(b1[0][0], bS0, 36864); R16(b1[0][1], bS1, 36864);          \
  R16(b1[1][0], bS0, 38912); R16(b1[1][1], bS1, 38912)

#define R_AH_0()                                                 \
  R16(aH[0][0], aS0, 8192);  R16(aH[0][1], aS1, 8192);           \
  R16(aH[1][0], aS0, 10240); R16(aH[1][1], aS1, 10240);          \
  R16(aH[2][0], aS0, 12288); R16(aH[2][1], aS1, 12288);          \
  R16(aH[3][0], aS0, 14336); R16(aH[3][1], aS1, 14336)

#define R_AH_1()                                                 \
  R16(aH[0][0], aS0, 40960); R16(aH[0][1], aS1, 40960);          \
  R16(aH[1][0], aS0, 43008); R16(aH[1][1], aS1, 43008);          \
  R16(aH[2][0], aS0, 45056); R16(aH[2][1], aS1, 45056);          \
  R16(aH[3][0], aS0, 47104); R16(aH[3][1], aS1, 47104)

#define MF(d, x, y) d = __builtin_amdgcn_mfma_f32_16x16x32_f16(x, y, d, 0, 0, 0)

#define PH0(B0)                                          \
  _Pragma("unroll") for (int i = 0; i < 4; ++i)          \
  _Pragma("unroll") for (int j = 0; j < 2; ++j) {        \
    MF(acc[i][j], aL[i][0], B0[j][0]);                   \
    MF(acc[i][j], aL[i][1], B0[j][1]);                   \
  }
#define PH1()                                            \
  _Pragma("unroll") for (int i = 0; i < 4; ++i)          \
  _Pragma("unroll") for (int j = 0; j < 2; ++j) {        \
    MF(acc[i][2 + j], aL[i][0], b1[j][0]);               \
    MF(acc[i][2 + j], aL[i][1], b1[j][1]);               \
  }
#define PH2()                                            \
  _Pragma("unroll") for (int i = 0; i < 4; ++i)          \
  _Pragma("unroll") for (int j = 0; j < 2; ++j) {        \
    MF(acc[4 + i][2 + j], aH[i][0], b1[j][0]);           \
    MF(acc[4 + i][2 + j], aH[i][1], b1[j][1]);           \
  }
#define PH3(B0)                                          \
  _Pragma("unroll") for (int i = 0; i < 4; ++i)          \
  _Pragma("unroll") for (int j = 0; j < 2; ++j) {        \
    MF(acc[4 + i][j], aH[i][0], B0[j][0]);               \
    MF(acc[4 + i][j], aH[i][1], B0[j][1]);               \
  }

#define PRIO1() __builtin_amdgcn_s_setprio(1)
#define PRIO0() __builtin_amdgcn_s_setprio(0)

  // prologue: stage tiles 0,1; wait own tile-0 loads; barrier (all waves'
  // tile-0 loads done); entry reads for tile 0.
  stage(0, 0);
  stage(1, 1);
  VMCNT(8);
  BAR();
  R_ENTRY_B0();

  for (int kt = 0; kt < NKT; kt += 2) {
    // ================= even tile kt (buf0, set A) =================
    R_B1_0();                               // 4 reads; outstanding 12+4
    LGKM(4); SB0(); PRIO1(); PH0(b0A); PRIO0();   // entry reads drained
    R_AH_0();                               // 8 reads; outstanding 4+8
    LGKM(8); SB0(); PRIO1(); PH1(); PRIO0();      // b1 drained
    LGKM(0); SB0(); PRIO1(); PH2(); PRIO0();      // aH drained
    VMCNT(0);  // stage(buf1, kt+1) — issued one full tile ago
    BAR();     // buf1 ready for reads; all waves done reading buf0
    R_ENTRY_B1();                           // 12 reads for tile kt+1
    if (kt + 2 < NKT) stage(0, kt + 2);     // overwrite buf0 (safe post-BAR)
    SB0(); PRIO1(); PH3(b0A); PRIO0();      // operands already in regs

    // ================= odd tile kt+1 (buf1, set B) ================
    R_B1_1();
    LGKM(4); SB0(); PRIO1(); PH0(b0B); PRIO0();
    R_AH_1();
    LGKM(8); SB0(); PRIO1(); PH1(); PRIO0();
    LGKM(0); SB0(); PRIO1(); PH2(); PRIO0();
    VMCNT(0);  // stage(buf0, kt+2) — issued above, one tile ago
    BAR();
    if (kt + 2 < NKT) {
      R_ENTRY_B0();                         // 12 reads for tile kt+2
      if (kt + 3 < NKT) stage(1, kt + 3);
    }
    SB0(); PRIO1(); PH3(b0B); PRIO0();
  }

  // ---- epilogue: C/D layout col = lane&15, row = (lane>>4)*4 + reg
  const int ccol0 = bn * 256 + wn * 64 + fr;
  const int crow0 = bm * 256 + wm * 128 + fq * 4;
  float bv[4];
#pragma unroll
  for (int j = 0; j < 4; ++j) bv[j] = bias[ccol0 + j * 16];
#pragma unroll
  for (int i = 0; i < 8; ++i) {
#pragma unroll
    for (int r = 0; r < 4; ++r) {
      float* cp = C + (size_t)(crow0 + i * 16 + r) * Nd + ccol0;
#pragma unroll
      for (int j = 0; j < 4; ++j) cp[j * 16] = acc[i][j][r] + bv[j];
    }
  }
}

extern "C" void kernel_launch(void* const* d_in, const int* in_sizes, int n_in,
                              void* d_out, int out_size, void* d_ws, size_t ws_size,
                              hipStream_t stream) {
  const float* inp = (const float*)d_in[0];
  const float* lut = (const float*)d_in[1];
  const int* wgt = (const int*)d_in[2];
  const float* bias = (const float*)d_in[3];
  float* out = (float*)d_out;

  _Float16* Ah = (_Float16*)d_ws;
  _Float16* Bh = (_Float16*)d_ws + (size_t)Md * Kd;

  cvt_a<<<(Md * (size_t)Kd) / (8 * 256), 256, 0, stream>>>(inp, Ah);
  dequant_b<<<((size_t)Nd * Kd) / (8 * 256), 256, 0, stream>>>(wgt, lut, Bh);

  dim3 grid(Md / 256, Nd / 256);  // (32, 16) = 512 blocks
  gemm_f16<<<grid, 512, 0, stream>>>(Ah, Bh, bias, out);
}